// Round 3
// baseline (170.104 us; speedup 1.0000x reference)
//
#include <hip/hip_runtime.h>

// Problem constants (fixed by setup_inputs): mask [64,480,864] fp32.
constexpr int B = 64;
constexpr int H = 480;
constexpr int W = 864;
constexpr float PROB_THRESHOLD = 0.5f;

constexpr int BPS = 16;                        // blocks per sample (power of 2)
constexpr int ROWS_PER_BLK = H / BPS;          // 30
constexpr int W4 = W / 4;                      // 216 float4 per row
constexpr int N4_PER_BLK = ROWS_PER_BLK * W4;  // 6480 float4 per block
constexpr int NBLK = B * BPS;                  // 1024 blocks = 4/CU x 256 CUs
constexpr int NPAIRS = ROWS_PER_BLK / 2;       // 15 outside-in row pairs

using f32x4 = __attribute__((ext_vector_type(4))) float;
using u64 = unsigned long long;

// Packed partial: minr:9 @0 | maxr+1:9 @9 | minc:10 @18 | maxc+1:10 @28 |
// cnt(sat 4095):12 @38 | zeros @50..55 | marker 0xFF @56.
// Workspace poison is 0xAAAA... (top byte 0xAA != 0xFF) -> no init pass.
constexpr u64 MARKER = 0xFFull << 56;

__device__ inline u64 pack_partial(int minr, int maxr, int minc, int maxc,
                                   int cnt) {
  u64 v = (u64)(unsigned)minr | ((u64)(unsigned)(maxr + 1) << 9) |
          ((u64)(unsigned)minc << 18) | ((u64)(unsigned)(maxc + 1) << 28) |
          ((u64)(unsigned)min(cnt, 4095) << 38) | MARKER;
  return v;
}

// ---------------------------------------------------------------------------
// R3 structure — the barrier is OFF the hot path:
//   Certain-1 lemma: global y0 = clip(minr-loose) <= clip(obs_minr-loose)
//   (minr <= any observed hit row), same for the other 3 edges; and in the
//   cnt<thr case every pixel is 1 anyway. So the rectangle built from a
//   block's OWN observed extremes, loosened and clipped, is certainly 1 for
//   ANY input. When the early-stop fires (hits observed at rows row0 and
//   row0+29, cols 0 and W-1, block cnt >= thr), that rectangle covers the
//   block's whole slab (loose >= 0). Stopped blocks therefore: publish their
//   packed partial, NT-store their slab = 1.0f, and EXIT -- no poll, no fold,
//   no cross-block visibility stall. Only blk==0 (writes the 16-B bbox, poll
//   hidden behind the device-wide store drain) and fallback blocks that never
//   stopped (their slab may contain 0s) take the exact poll+fold path, which
//   is preserved unchanged for arbitrary inputs.
// Phase 1: early-terminating outside-in row-pair scan (R1 proof), pair 0
//   unprefetched, parity-indexed vote slots -> one __syncthreads per pair.
// Publish/poll: fenceless relaxed agent-scope atomics, payload inside the
//   word (release fences collapsed BW to 1.9 TB/s in the earlier session).
// ---------------------------------------------------------------------------
__global__ __launch_bounds__(256, 4) void fused_kernel(
    const float* __restrict__ mask, const int* __restrict__ n_pts_threshold,
    const int* __restrict__ n_bbox_loose, float* __restrict__ out,
    float* __restrict__ bbox_out, u64* __restrict__ part) {
  const int b    = blockIdx.x >> 4;  // / BPS
  const int blk  = blockIdx.x & 15;  // % BPS
  const int row0 = blk * ROWS_PER_BLK;
  const f32x4* __restrict__ m4 =
      (const f32x4*)(mask + ((size_t)b * H + row0) * (size_t)W);

  const int thr = n_pts_threshold[0];
  const int tid = threadIdx.x;
  const int wave = tid >> 6;
  const int lane = tid & 63;

  // Per-thread fixed geometry: pair s covers rows t=s and bb=29-s (relative).
  // Elem A: tid<216 -> (row t, col4 tid); tid>=216 -> (row bb, col4 tid-216).
  // Elem B (tid<176): (row bb, col4 tid+40). Row bb thus covered 0..215.
  const bool aTop = tid < W4;
  const int aC4   = aTop ? tid : tid - W4;
  const bool hasB = tid < (2 * W4 - 256);   // 176
  const int bC4   = tid + (256 - W4);       // tid + 40
  const int aC = aC4 * 4, bC = bC4 * 4;

  int minr = H, maxr = -1, minc = W, maxc = -1, cnt = 0;

  auto proc = [&](f32x4 v, int row, int c) {
    bool h0 = v.x > PROB_THRESHOLD;
    bool h1 = v.y > PROB_THRESHOLD;
    bool h2 = v.z > PROB_THRESHOLD;
    bool h3 = v.w > PROB_THRESHOLD;
    int m = (h0 ? 1 : 0) | (h1 ? 2 : 0) | (h2 ? 4 : 0) | (h3 ? 8 : 0);
    if (m) {
      minr = min(minr, row);
      maxr = max(maxr, row);
      minc = min(minc, c + (__ffs(m) - 1));
      maxc = max(maxc, c + (31 - __clz(m)));
      cnt += __popc(m);
    }
  };

  auto loadA = [&](int s) {
    int rr = aTop ? s : (ROWS_PER_BLK - 1 - s);
    return __builtin_nontemporal_load(&m4[rr * W4 + aC4]);
  };
  auto loadB = [&](int s) {
    return __builtin_nontemporal_load(&m4[(ROWS_PER_BLK - 1 - s) * W4 + bC4]);
  };

  __shared__ int vfl[2][4];   // parity-indexed per-wave vote: extreme flags
  __shared__ int vcn[2][4];   // parity-indexed per-wave vote: hit count
  __shared__ int s5[4][5];    // fallback exact cross-wave reduce
  __shared__ u64 packed[BPS];

  // Block-wide stop check, ONE barrier per pair via parity slots.
  auto stopCheck = [&](int s) -> bool {
    int wc = cnt;
    for (int off = 1; off < 64; off <<= 1) wc += __shfl_xor(wc, off);
    int fl = (__any(minr == row0) ? 1 : 0) |
             (__any(maxr == row0 + ROWS_PER_BLK - 1) ? 2 : 0) |
             (__any(minc == 0) ? 4 : 0) |
             (__any(maxc == W - 1) ? 8 : 0);
    const int p = s & 1;
    if (lane == 0) { vfl[p][wave] = fl; vcn[p][wave] = wc; }
    __syncthreads();
    const int bfl  = vfl[p][0] | vfl[p][1] | vfl[p][2] | vfl[p][3];
    const int bcnt = vcn[p][0] + vcn[p][1] + vcn[p][2] + vcn[p][3];
    return (bfl == 15) & (bcnt >= thr);
  };

  bool stopped;
  {  // pair 0: no prefetch -> stopping blocks read exactly 2 rows.
    f32x4 ca = loadA(0), cb{};
    if (hasB) cb = loadB(0);
    proc(ca, aTop ? row0 : row0 + ROWS_PER_BLK - 1, aC);
    if (hasB) proc(cb, row0 + ROWS_PER_BLK - 1, bC);
    stopped = stopCheck(0);
  }
  if (!stopped) {
    f32x4 pa = loadA(1), pb{};
    if (hasB) pb = loadB(1);
    for (int s = 1; s < NPAIRS; ++s) {
      f32x4 ca = pa, cb = pb;
      const int sn = (s + 1 < NPAIRS) ? s + 1 : s;  // clamped prefetch
      pa = loadA(sn);
      if (hasB) pb = loadB(sn);
      const int rt = row0 + s;
      const int rb = row0 + ROWS_PER_BLK - 1 - s;
      proc(ca, aTop ? rt : rb, aC);
      if (hasB) proc(cb, rb, bC);
      if ((stopped = stopCheck(s))) break;
    }
  }

  u64* __restrict__ P = part + (size_t)b * BPS;  // this sample's slots
  f32x4* obase = (f32x4*)(out + ((size_t)b * H + row0) * (size_t)W);

  if (stopped) {
    // Publish (extremes observed -> exact bbox fields; cnt>=thr -> saturated
    // count is decision-equivalent).
    if (tid == 0)
      __hip_atomic_store(
          &P[blk],
          pack_partial(row0, row0 + ROWS_PER_BLK - 1, 0, W - 1, 4095),
          __ATOMIC_RELAXED, __HIP_MEMORY_SCOPE_AGENT);

    // Certain-1 covers the whole slab: store 1.0f immediately, no barrier.
    f32x4 ones;
    ones.x = 1.0f; ones.y = 1.0f; ones.z = 1.0f; ones.w = 1.0f;
    int i = tid;
#pragma unroll
    for (int k = 0; k < 25; ++k, i += 256)
      __builtin_nontemporal_store(ones, &obase[i]);
    if (i < N4_PER_BLK) __builtin_nontemporal_store(ones, &obase[i]);

    // Only blk 0 needs the global fold (for the 16-B bbox output); its poll
    // overlaps the device-wide store drain of the other 1023 blocks.
    if (blk == 0) {
      if (tid < BPS) {
        u64 v;
        while (((v = __hip_atomic_load(&P[tid], __ATOMIC_RELAXED,
                                       __HIP_MEMORY_SCOPE_AGENT)) >> 56) !=
               0xFF)
          __builtin_amdgcn_s_sleep(2);
        packed[tid] = v;
      }
      __syncthreads();
      if (tid == 0) {
        int mnr = H, mxr = -1, mnc = W, mxc = -1, c2 = 0;
#pragma unroll
        for (int k = 0; k < BPS; ++k) {
          u64 v = packed[k];
          mnr = min(mnr, (int)(v & 511));
          mxr = max(mxr, (int)((v >> 9) & 511) - 1);
          mnc = min(mnc, (int)((v >> 18) & 1023));
          mxc = max(mxc, (int)((v >> 28) & 1023) - 1);
          c2 += (int)((v >> 38) & 4095);
        }
        const int loose = n_bbox_loose[0];
        int y0, y1, x0, x1;
        if (c2 < thr) {
          y0 = 0; y1 = H - 1; x0 = 0; x1 = W - 1;
        } else {
          y0 = min(max(mnr - loose, 0), H - 1);
          y1 = min(max(mxr + loose, 0), H - 1);
          x0 = min(max(mnc - loose, 0), W - 1);
          x1 = min(max(mxc + loose, 0), W - 1);
        }
        bbox_out[b * 4 + 0] = (float)y0;
        bbox_out[b * 4 + 1] = (float)y1;
        bbox_out[b * 4 + 2] = (float)x0;
        bbox_out[b * 4 + 3] = (float)x1;
      }
    }
    return;
  }

  // ---- Fallback (rare; exact for arbitrary inputs) ----
  for (int off = 32; off > 0; off >>= 1) {
    minr = min(minr, __shfl_down(minr, off));
    maxr = max(maxr, __shfl_down(maxr, off));
    minc = min(minc, __shfl_down(minc, off));
    maxc = max(maxc, __shfl_down(maxc, off));
    cnt += __shfl_down(cnt, off);
  }
  if (lane == 0) {
    s5[wave][0] = minr; s5[wave][1] = maxr;
    s5[wave][2] = minc; s5[wave][3] = maxc;
    s5[wave][4] = cnt;
  }
  __syncthreads();
  if (tid == 0) {
    for (int wv = 1; wv < 4; ++wv) {
      minr = min(minr, s5[wv][0]);
      maxr = max(maxr, s5[wv][1]);
      minc = min(minc, s5[wv][2]);
      maxc = max(maxc, s5[wv][3]);
      cnt += s5[wv][4];
    }
    __hip_atomic_store(&P[blk], pack_partial(minr, maxr, minc, maxc, cnt),
                       __ATOMIC_RELAXED, __HIP_MEMORY_SCOPE_AGENT);
  }

  // Per-sample barrier: fenceless relaxed polls.
  if (tid < BPS) {
    u64 v;
    while (((v = __hip_atomic_load(&P[tid], __ATOMIC_RELAXED,
                                   __HIP_MEMORY_SCOPE_AGENT)) >> 56) != 0xFF)
      __builtin_amdgcn_s_sleep(2);
    packed[tid] = v;
  }
  __syncthreads();

  // Fold packed partials (LDS broadcast) + predicate fill.
  minr = H; maxr = -1; minc = W; maxc = -1; cnt = 0;
#pragma unroll
  for (int k = 0; k < BPS; ++k) {
    u64 v = packed[k];
    minr = min(minr, (int)(v & 511));
    maxr = max(maxr, (int)((v >> 9) & 511) - 1);
    minc = min(minc, (int)((v >> 18) & 1023));
    maxc = max(maxc, (int)((v >> 28) & 1023) - 1);
    cnt += (int)((v >> 38) & 4095);  // saturated at 4095 >= thr=10: OK
  }
  const int loose = n_bbox_loose[0];
  int y0, y1, x0, x1;
  if (cnt < thr) {
    y0 = 0; y1 = H - 1; x0 = 0; x1 = W - 1;
  } else {
    y0 = min(max(minr - loose, 0), H - 1);
    y1 = min(max(maxr + loose, 0), H - 1);
    x0 = min(max(minc - loose, 0), W - 1);
    x1 = min(max(maxc + loose, 0), W - 1);
  }
  if (blk == 0 && tid == 0) {
    bbox_out[b * 4 + 0] = (float)y0;
    bbox_out[b * 4 + 1] = (float)y1;
    bbox_out[b * 4 + 2] = (float)x0;
    bbox_out[b * 4 + 3] = (float)x1;
  }

  // Row-structured write: thread t<216 owns column-group t for all 30 rows.
  if (tid < W4) {
    const int c = tid * 4;
    f32x4 colv, zero;
    colv.x = ((c + 0 >= x0) & (c + 0 <= x1)) ? 1.0f : 0.0f;
    colv.y = ((c + 1 >= x0) & (c + 1 <= x1)) ? 1.0f : 0.0f;
    colv.z = ((c + 2 >= x0) & (c + 2 <= x1)) ? 1.0f : 0.0f;
    colv.w = ((c + 3 >= x0) & (c + 3 <= x1)) ? 1.0f : 0.0f;
    zero.x = 0.0f; zero.y = 0.0f; zero.z = 0.0f; zero.w = 0.0f;

    f32x4* p = obase + tid;
    int rr = row0;
#pragma unroll
    for (int r = 0; r < ROWS_PER_BLK; ++r, ++rr, p += W4) {
      const bool inr = (rr >= y0) & (rr <= y1);
      __builtin_nontemporal_store(inr ? colv : zero, p);
    }
  }
}

extern "C" void kernel_launch(void* const* d_in, const int* in_sizes, int n_in,
                              void* d_out, int out_size, void* d_ws,
                              size_t ws_size, hipStream_t stream) {
  const float* mask = (const float*)d_in[0];
  const int* n_pts_threshold = (const int*)d_in[1];
  const int* n_bbox_loose = (const int*)d_in[2];

  float* out = (float*)d_out;
  float* bbox_out = out + (size_t)B * H * W;  // tuple outputs concatenated
  u64* part = (u64*)d_ws;                     // NBLK * 8 B

  fused_kernel<<<NBLK, 256, 0, stream>>>(mask, n_pts_threshold, n_bbox_loose,
                                         out, bbox_out, part);
}

// Round 4
// 167.122 us; speedup vs baseline: 1.0178x; 1.0178x over previous
//
#include <hip/hip_runtime.h>

// Problem constants (fixed by setup_inputs): mask [64,480,864] fp32.
constexpr int B = 64;
constexpr int H = 480;
constexpr int W = 864;
constexpr float PROB_THRESHOLD = 0.5f;

constexpr int BPS = 16;                        // blocks per sample (power of 2)
constexpr int ROWS_PER_BLK = H / BPS;          // 30
constexpr int W4 = W / 4;                      // 216 float4 per row
constexpr int N4_PER_BLK = ROWS_PER_BLK * W4;  // 6480 float4 per block
constexpr int NBLK = B * BPS;                  // 1024 blocks = 4/CU x 256 CUs
constexpr int NPAIRS = ROWS_PER_BLK / 2;       // 15 outside-in row pairs

using f32x4 = __attribute__((ext_vector_type(4))) float;
using u64 = unsigned long long;

// Packed partial: minr:9 @0 | maxr+1:9 @9 | minc:10 @18 | maxc+1:10 @28 |
// cnt(sat 4095):12 @38 | zeros @50..55 | marker 0xFF @56.
// Workspace poison is 0xAAAA... (top byte 0xAA != 0xFF) -> no init pass.
constexpr u64 MARKER = 0xFFull << 56;

__device__ inline u64 pack_partial(int minr, int maxr, int minc, int maxc,
                                   int cnt) {
  u64 v = (u64)(unsigned)minr | ((u64)(unsigned)(maxr + 1) << 9) |
          ((u64)(unsigned)minc << 18) | ((u64)(unsigned)(maxc + 1) << 28) |
          ((u64)(unsigned)min(cnt, 4095) << 38) | MARKER;
  return v;
}

// ---------------------------------------------------------------------------
// R4 = revert to R2 (best measured: 167.1 us). R3's certain-1 early-exit
// restructure regressed (+3.0 us vs prediction of -4..-8): the pre-store
// publish/poll stall was NOT on the critical path. Keeping the simpler,
// best-measured structure:
// Phase 1: EARLY-TERMINATING outside-in row-pair scan (partial is final once
//   hits observed at slab-extreme rows + global column extremes with
//   cnt >= thr). Pair 0 unprefetched; parity-indexed vote slots -> one
//   __syncthreads per pair. Worst case degrades to full scan + exact reduce.
// Barrier: fenceless per-sample relaxed agent-scope publish/poll (payload
//   inside the atomic word; release fences collapsed BW to 1.9 TB/s).
// Phase 2: row-structured NT store: thread t<216 owns column-group t for all
//   30 rows; column predicate vector computed ONCE, per row one cndmask+store.
// ---------------------------------------------------------------------------
__global__ __launch_bounds__(256, 4) void fused_kernel(
    const float* __restrict__ mask, const int* __restrict__ n_pts_threshold,
    const int* __restrict__ n_bbox_loose, float* __restrict__ out,
    float* __restrict__ bbox_out, u64* __restrict__ part) {
  const int b    = blockIdx.x >> 4;  // / BPS
  const int blk  = blockIdx.x & 15;  // % BPS
  const int row0 = blk * ROWS_PER_BLK;
  const f32x4* __restrict__ m4 =
      (const f32x4*)(mask + ((size_t)b * H + row0) * (size_t)W);

  const int thr = n_pts_threshold[0];
  const int tid = threadIdx.x;
  const int wave = tid >> 6;
  const int lane = tid & 63;

  // Per-thread fixed geometry: pair s covers rows t=s and bb=29-s (relative).
  // Elem A: tid<216 -> (row t, col4 tid); tid>=216 -> (row bb, col4 tid-216).
  // Elem B (tid<176): (row bb, col4 tid+40). Row bb thus covered 0..215.
  const bool aTop = tid < W4;
  const int aC4   = aTop ? tid : tid - W4;
  const bool hasB = tid < (2 * W4 - 256);   // 176
  const int bC4   = tid + (256 - W4);       // tid + 40
  const int aC = aC4 * 4, bC = bC4 * 4;

  int minr = H, maxr = -1, minc = W, maxc = -1, cnt = 0;

  auto proc = [&](f32x4 v, int row, int c) {
    bool h0 = v.x > PROB_THRESHOLD;
    bool h1 = v.y > PROB_THRESHOLD;
    bool h2 = v.z > PROB_THRESHOLD;
    bool h3 = v.w > PROB_THRESHOLD;
    int m = (h0 ? 1 : 0) | (h1 ? 2 : 0) | (h2 ? 4 : 0) | (h3 ? 8 : 0);
    if (m) {
      minr = min(minr, row);
      maxr = max(maxr, row);
      minc = min(minc, c + (__ffs(m) - 1));
      maxc = max(maxc, c + (31 - __clz(m)));
      cnt += __popc(m);
    }
  };

  auto loadA = [&](int s) {
    int rr = aTop ? s : (ROWS_PER_BLK - 1 - s);
    return __builtin_nontemporal_load(&m4[rr * W4 + aC4]);
  };
  auto loadB = [&](int s) {
    return __builtin_nontemporal_load(&m4[(ROWS_PER_BLK - 1 - s) * W4 + bC4]);
  };

  __shared__ int vfl[2][4];   // parity-indexed per-wave vote: extreme flags
  __shared__ int vcn[2][4];   // parity-indexed per-wave vote: hit count
  __shared__ int s5[4][5];    // fallback exact cross-wave reduce
  __shared__ u64 packed[BPS];

  // Block-wide stop check, ONE barrier per pair via parity slots.
  auto stopCheck = [&](int s) -> bool {
    int wc = cnt;
    for (int off = 1; off < 64; off <<= 1) wc += __shfl_xor(wc, off);
    int fl = (__any(minr == row0) ? 1 : 0) |
             (__any(maxr == row0 + ROWS_PER_BLK - 1) ? 2 : 0) |
             (__any(minc == 0) ? 4 : 0) |
             (__any(maxc == W - 1) ? 8 : 0);
    const int p = s & 1;
    if (lane == 0) { vfl[p][wave] = fl; vcn[p][wave] = wc; }
    __syncthreads();
    const int bfl  = vfl[p][0] | vfl[p][1] | vfl[p][2] | vfl[p][3];
    const int bcnt = vcn[p][0] + vcn[p][1] + vcn[p][2] + vcn[p][3];
    return (bfl == 15) & (bcnt >= thr);
  };

  bool stopped;
  {  // pair 0: no prefetch -> stopping blocks read exactly 2 rows.
    f32x4 ca = loadA(0), cb{};
    if (hasB) cb = loadB(0);
    proc(ca, aTop ? row0 : row0 + ROWS_PER_BLK - 1, aC);
    if (hasB) proc(cb, row0 + ROWS_PER_BLK - 1, bC);
    stopped = stopCheck(0);
  }
  if (!stopped) {
    f32x4 pa = loadA(1), pb{};
    if (hasB) pb = loadB(1);
    for (int s = 1; s < NPAIRS; ++s) {
      f32x4 ca = pa, cb = pb;
      const int sn = (s + 1 < NPAIRS) ? s + 1 : s;  // clamped prefetch
      pa = loadA(sn);
      if (hasB) pb = loadB(sn);
      const int rt = row0 + s;
      const int rb = row0 + ROWS_PER_BLK - 1 - s;
      proc(ca, aTop ? rt : rb, aC);
      if (hasB) proc(cb, rb, bC);
      if ((stopped = stopCheck(s))) break;
    }
  }

  u64* __restrict__ P = part + (size_t)b * BPS;  // this sample's slots
  if (stopped) {
    // Extremes were OBSERVED (real hits) -> partial exact for bbox fields;
    // cnt>=thr -> saturated publish is decision-equivalent.
    if (tid == 0)
      __hip_atomic_store(
          &P[blk],
          pack_partial(row0, row0 + ROWS_PER_BLK - 1, 0, W - 1, 4095),
          __ATOMIC_RELAXED, __HIP_MEMORY_SCOPE_AGENT);
  } else {
    // Fallback: exact full reduce (wave shuffle + LDS), as before.
    for (int off = 32; off > 0; off >>= 1) {
      minr = min(minr, __shfl_down(minr, off));
      maxr = max(maxr, __shfl_down(maxr, off));
      minc = min(minc, __shfl_down(minc, off));
      maxc = max(maxc, __shfl_down(maxc, off));
      cnt += __shfl_down(cnt, off);
    }
    if (lane == 0) {
      s5[wave][0] = minr; s5[wave][1] = maxr;
      s5[wave][2] = minc; s5[wave][3] = maxc;
      s5[wave][4] = cnt;
    }
    __syncthreads();
    if (tid == 0) {
      for (int wv = 1; wv < 4; ++wv) {
        minr = min(minr, s5[wv][0]);
        maxr = max(maxr, s5[wv][1]);
        minc = min(minc, s5[wv][2]);
        maxc = max(maxc, s5[wv][3]);
        cnt += s5[wv][4];
      }
      __hip_atomic_store(&P[blk], pack_partial(minr, maxr, minc, maxc, cnt),
                         __ATOMIC_RELAXED, __HIP_MEMORY_SCOPE_AGENT);
    }
  }

  // ---- Per-sample barrier: fenceless relaxed polls ----
  if (tid < BPS) {
    u64 v;
    while (((v = __hip_atomic_load(&P[tid], __ATOMIC_RELAXED,
                                   __HIP_MEMORY_SCOPE_AGENT)) >> 56) != 0xFF)
      __builtin_amdgcn_s_sleep(2);
    packed[tid] = v;
  }
  __syncthreads();

  // ---- Phase 2: fold packed partials (LDS broadcast) + fill ----
  minr = H; maxr = -1; minc = W; maxc = -1; cnt = 0;
#pragma unroll
  for (int k = 0; k < BPS; ++k) {
    u64 v = packed[k];
    minr = min(minr, (int)(v & 511));
    maxr = max(maxr, (int)((v >> 9) & 511) - 1);
    minc = min(minc, (int)((v >> 18) & 1023));
    maxc = max(maxc, (int)((v >> 28) & 1023) - 1);
    cnt += (int)((v >> 38) & 4095);  // saturated at 4095 >= thr=10: OK
  }
  const int loose = n_bbox_loose[0];
  int y0, y1, x0, x1;
  if (cnt < thr) {
    y0 = 0; y1 = H - 1; x0 = 0; x1 = W - 1;
  } else {
    y0 = min(max(minr - loose, 0), H - 1);
    y1 = min(max(maxr + loose, 0), H - 1);
    x0 = min(max(minc - loose, 0), W - 1);
    x1 = min(max(maxc + loose, 0), W - 1);
  }
  if (blk == 0 && tid == 0) {
    bbox_out[b * 4 + 0] = (float)y0;
    bbox_out[b * 4 + 1] = (float)y1;
    bbox_out[b * 4 + 2] = (float)x0;
    bbox_out[b * 4 + 3] = (float)x1;
  }

  // Row-structured write: thread t<216 owns column-group t for all 30 rows.
  // Column predicate computed once; per row: one vector select + NT store.
  if (tid < W4) {
    const int c = tid * 4;
    f32x4 colv, zero;
    colv.x = ((c + 0 >= x0) & (c + 0 <= x1)) ? 1.0f : 0.0f;
    colv.y = ((c + 1 >= x0) & (c + 1 <= x1)) ? 1.0f : 0.0f;
    colv.z = ((c + 2 >= x0) & (c + 2 <= x1)) ? 1.0f : 0.0f;
    colv.w = ((c + 3 >= x0) & (c + 3 <= x1)) ? 1.0f : 0.0f;
    zero.x = 0.0f; zero.y = 0.0f; zero.z = 0.0f; zero.w = 0.0f;

    f32x4* p = (f32x4*)(out + ((size_t)b * H + row0) * (size_t)W) + tid;
    int rr = row0;
#pragma unroll
    for (int r = 0; r < ROWS_PER_BLK; ++r, ++rr, p += W4) {
      const bool inr = (rr >= y0) & (rr <= y1);
      __builtin_nontemporal_store(inr ? colv : zero, p);
    }
  }
}

extern "C" void kernel_launch(void* const* d_in, const int* in_sizes, int n_in,
                              void* d_out, int out_size, void* d_ws,
                              size_t ws_size, hipStream_t stream) {
  const float* mask = (const float*)d_in[0];
  const int* n_pts_threshold = (const int*)d_in[1];
  const int* n_bbox_loose = (const int*)d_in[2];

  float* out = (float*)d_out;
  float* bbox_out = out + (size_t)B * H * W;  // tuple outputs concatenated
  u64* part = (u64*)d_ws;                     // NBLK * 8 B

  fused_kernel<<<NBLK, 256, 0, stream>>>(mask, n_pts_threshold, n_bbox_loose,
                                         out, bbox_out, part);
}